// Round 6
// baseline (1169.536 us; speedup 1.0000x reference)
//
#include <hip/hip_runtime.h>
#include <hip/hip_bf16.h>
#include <stdint.h>

typedef __attribute__((ext_vector_type(8))) short short8;
typedef __attribute__((ext_vector_type(4))) float f32x4;
typedef unsigned short u16;

// ---------------- workspace layout (bytes) ----------------
#define OFF_PSUM 0ULL                      // 1e6*64*4 = 256,000,000
#define OFF_CNT  256000000ULL              // 1e6*4
#define OFF_EBF  260000000ULL              // 1e6*64*2 = 128,000,000
#define OFF_WT1  388000000ULL              // W1^T row-major [n][k]: 128*160*2 = 40960
#define OFF_WT2  (OFF_WT1 + 40960ULL)      // W2'^T row-major [n][k]: 128*128*2 = 32768
#define OFF_WP3  (OFF_WT2 + 32768ULL)      // W3' frag-packed [kb][n][8]: 16384
#define OFF_S2   (OFF_WP3 + 16384ULL)      // 128*4
#define OFF_C2   (OFF_S2 + 512ULL)         // 128*4
#define OFF_S3   (OFF_C2 + 512ULL)         // 64*4
#define OFF_T3   (OFF_S3 + 256ULL)         // 64*4

// ---------------- LDS layout (bytes), 64-trip block ----------------
#define LDS_HM   0        // [64 trip][256B] swizzled; H, then M aliases it
#define LDS_TAIL 16384    // [64 trip][64B] geo tail, swizzled (r&3)<<4
#define LDS_P1S  20480    // float[64][2]
#define LDS_P1Q  20992
#define LDS_P2S  21504
#define LDS_P2Q  22016
#define LDS_EIJ  22528    // int[64]
#define LDS_TOTAL 22784

__device__ __forceinline__ u16 f2bf(float f) {
  union { float f; uint32_t u; } c; c.f = f;
  uint32_t u = c.u;
  return (u16)((u + 0x7FFFu + ((u >> 16) & 1u)) >> 16);  // RNE
}
__device__ __forceinline__ uint32_t pkbf(float lo, float hi) {
  float2 t; t.x = lo; t.y = hi;
  __hip_bfloat162 h = __float22bfloat162_rn(t);
  uint32_t u; __builtin_memcpy(&u, &h, 4);
  return u;
}
__device__ __forceinline__ float silu(float y) {
  return y * __builtin_amdgcn_rcpf(1.0f + __expf(-y));
}

#define MFMA16(a, b, c) __builtin_amdgcn_mfma_f32_16x16x32_bf16((a), (b), (c), 0, 0, 0)

// ---------------- prep kernels ----------------

__global__ __launch_bounds__(256) void k_conv_edge(const float* __restrict__ ef,
                                                   u16* __restrict__ ebf) {
  int i = blockIdx.x * 256 + threadIdx.x;  // < 16,000,000
  float4 v = ((const float4*)ef)[i];
  ushort4 o;
  o.x = f2bf(v.x); o.y = f2bf(v.y); o.z = f2bf(v.z); o.w = f2bf(v.w);
  ((ushort4*)ebf)[i] = o;
}

// wt1[n*160+k] = W1[k,n] (k<132 else 0)   [transposed row-major]
// wt2[n*128+k] = g1[k]*W2[k,n]            [transposed row-major]
// wp3[(k>>3)*64 + n][k&7] = g2[k]*W3[k,n] [B-fragment packed]
__global__ __launch_bounds__(256) void k_pack_w(const float* __restrict__ W1,
                                                const float* __restrict__ W2,
                                                const float* __restrict__ W3,
                                                const float* __restrict__ g1,
                                                const float* __restrict__ g2,
                                                u16* __restrict__ wt1,
                                                u16* __restrict__ wt2,
                                                u16* __restrict__ wp3) {
  int i = blockIdx.x * 256 + threadIdx.x;  // < 45056
  if (i < 20480) {
    int n = i / 160, k = i - n * 160;
    wt1[i] = (k < 132) ? f2bf(W1[k * 128 + n]) : (u16)0;
  } else if (i < 36864) {
    int i2 = i - 20480;
    int n = i2 >> 7, k = i2 & 127;
    wt2[i2] = f2bf(g1[k] * W2[k * 128 + n]);
  } else if (i < 45056) {
    int i3 = i - 36864;
    int j = i3 & 7, n = (i3 >> 3) & 63, kb = i3 >> 9;
    int k = kb * 8 + j;
    wp3[i3] = f2bf(g2[k] * W3[k * 64 + n]);
  }
}

// fold vectors: s2[n]=sum_k g1[k]W2[k,n], c2[n]=sum_k be1[k]W2[k,n]+b2[n]
//               s3[n]=sum_k g2[k]W3[k,n], t3[n]=sum_k be2[k]W3[k,n]
__global__ __launch_bounds__(256) void k_pack_vec(
    const float* __restrict__ W2, const float* __restrict__ W3,
    const float* __restrict__ g1, const float* __restrict__ be1, const float* __restrict__ b2,
    const float* __restrict__ g2, const float* __restrict__ be2,
    float* __restrict__ s2, float* __restrict__ c2,
    float* __restrict__ s3, float* __restrict__ t3) {
  int t = threadIdx.x;
  if (t < 128) {
    float a = 0.f, b = 0.f;
    for (int k = 0; k < 128; ++k) {
      float w = W2[k * 128 + t];
      a += g1[k] * w; b += be1[k] * w;
    }
    s2[t] = a; c2[t] = b + b2[t];
  } else if (t < 192) {
    int n = t - 128;
    float a = 0.f, b = 0.f;
    for (int k = 0; k < 128; ++k) {
      float w = W3[k * 64 + n];
      a += g2[k] * w; b += be2[k] * w;
    }
    s3[n] = a; t3[n] = b;
  }
}

// ---------------- main triplet kernel ----------------
// 256 thr = 4 waves (wm:2 hidden-halves x wn:2 trip-halves), 64 triplets/block.
// GEMM1/2 transposed (lane-local LN stats); GEMM1 B-frags gathered from global
// (pinned with sched_barrier); GEMM2/3 weight frags software-pipelined 1-deep;
// GEMM3 un-transposed -> coalesced atomics. setprio(1) around MFMA clusters.

__global__ __launch_bounds__(256, 5) void k_triplet(
    const u16* __restrict__ ebf, const int* __restrict__ tidx,
    const float* __restrict__ geo,
    const u16* __restrict__ wt1, const u16* __restrict__ wt2, const u16* __restrict__ wp3,
    const float* __restrict__ b1,
    const float* __restrict__ s2v, const float* __restrict__ c2v,
    const float* __restrict__ s3v,
    float* __restrict__ psum, float* __restrict__ cnt) {
  __shared__ __align__(16) char smem[LDS_TOTAL];
  float* P1S = (float*)(smem + LDS_P1S);
  float* P1Q = (float*)(smem + LDS_P1Q);
  float* P2S = (float*)(smem + LDS_P2S);
  float* P2Q = (float*)(smem + LDS_P2Q);
  int* EIJ = (int*)(smem + LDS_EIJ);

  const int tid = threadIdx.x;
  const int wave = tid >> 6, lane = tid & 63;
  const int wm = wave >> 1, wn = wave & 1;
  const int l15 = lane & 15, lg = lane >> 4;
  const int t0 = blockIdx.x * 64;

  // per-lane trips for the two B-fragment columns (f=0,1)
  const int tA = wn * 32 + l15;
  const int tB = tA + 16;
  int2 pA = ((const int2*)tidx)[t0 + tA];
  int2 pB = ((const int2*)tidx)[t0 + tB];

  // 8 global B-frag gathers (16B each) for GEMM1 (k<128 part) -- pinned early
  const short8* eb = (const short8*)ebf;
  short8 bxA0 = eb[(size_t)pA.x * 8 + lg];
  short8 bxA1 = eb[(size_t)pA.x * 8 + 4 + lg];
  short8 bxA2 = eb[(size_t)pA.y * 8 + lg];
  short8 bxA3 = eb[(size_t)pA.y * 8 + 4 + lg];
  short8 bxB0 = eb[(size_t)pB.x * 8 + lg];
  short8 bxB1 = eb[(size_t)pB.x * 8 + 4 + lg];
  short8 bxB2 = eb[(size_t)pB.y * 8 + lg];
  short8 bxB3 = eb[(size_t)pB.y * 8 + 4 + lg];
  __builtin_amdgcn_sched_barrier(0);  // forbid sinking the gathers

  // stage EIJ + geo tail ([64][64B], swizzle (r&3)<<4)
  if (tid < 64) {
    int2 p = ((const int2*)tidx)[t0 + tid];
    EIJ[tid] = p.x;
    atomicAdd(&cnt[p.x], 1.0f);
    float4 gq = ((const float4*)geo)[t0 + tid];
    uint2 gw; gw.x = pkbf(gq.x, gq.y); gw.y = pkbf(gq.z, gq.w);
    char* tp = smem + LDS_TAIL + tid * 64;
    const int ts = (tid & 3) << 4;
    *(uint2*)(tp + (0 ^ ts)) = gw;
    *(uint2*)(tp + (0 ^ ts) + 8) = (uint2){0, 0};
    *(uint4*)(tp + (16 ^ ts)) = (uint4){0, 0, 0, 0};
    *(uint4*)(tp + (32 ^ ts)) = (uint4){0, 0, 0, 0};
    *(uint4*)(tp + (48 ^ ts)) = (uint4){0, 0, 0, 0};
  }
  __syncthreads();

  short8 btA = *(const short8*)(smem + LDS_TAIL + tA * 64 + ((lg * 16) ^ ((tA & 3) << 4)));
  short8 btB = *(const short8*)(smem + LDS_TAIL + tB * 64 + ((lg * 16) ^ ((tB & 3) << 4)));

  // ---- GEMM1: C1' = W1^T x X^T  (K=160), weights JIT (VGPR budget) ----
  f32x4 acc[4][2];
#pragma unroll
  for (int mf = 0; mf < 4; ++mf) { acc[mf][0] = (f32x4)0.f; acc[mf][1] = (f32x4)0.f; }
  const short8* w1p = (const short8*)wt1;
#pragma unroll
  for (int s5 = 0; s5 < 5; ++s5) {
    short8 b0, b1x;
    if (s5 == 0) { b0 = bxA0; b1x = bxB0; }
    else if (s5 == 1) { b0 = bxA1; b1x = bxB1; }
    else if (s5 == 2) { b0 = bxA2; b1x = bxB2; }
    else if (s5 == 3) { b0 = bxA3; b1x = bxB3; }
    else { b0 = btA; b1x = btB; }
    short8 aw[4];
#pragma unroll
    for (int mf = 0; mf < 4; ++mf)
      aw[mf] = w1p[(wm * 64 + mf * 16 + l15) * 20 + s5 * 4 + lg];
    __builtin_amdgcn_s_setprio(1);
#pragma unroll
    for (int mf = 0; mf < 4; ++mf) {
      acc[mf][0] = MFMA16(aw[mf], b0, acc[mf][0]);
      acc[mf][1] = MFMA16(aw[mf], b1x, acc[mf][1]);
    }
    __builtin_amdgcn_s_setprio(0);
  }

  // pre-issue GEMM2 step-0 weight frags (covered by epilogue-1 VALU)
  const short8* w2p = (const short8*)wt2;
  short8 w2c[4];
#pragma unroll
  for (int mf = 0; mf < 4; ++mf)
    w2c[mf] = w2p[(wm * 64 + mf * 16 + l15) * 16 + lg];

  // epilogue1: bias+silu; lane-local stats; write H^T [trip][n] bf16
  {
    float4 b1f[4];
#pragma unroll
    for (int mf = 0; mf < 4; ++mf)
      b1f[mf] = *(const float4*)(b1 + wm * 64 + mf * 16 + lg * 4);
    float st[2] = {0.f, 0.f}, sq[2] = {0.f, 0.f};
#pragma unroll
    for (int mf = 0; mf < 4; ++mf)
#pragma unroll
      for (int f = 0; f < 2; ++f)
#pragma unroll
        for (int q = 0; q < 4; ++q) {
          float v = silu(acc[mf][f][q] + b1f[mf][q]);
          acc[mf][f][q] = v;
          st[f] += v; sq[f] += v * v;
        }
#pragma unroll
    for (int f = 0; f < 2; ++f) {
      st[f] += __shfl_xor(st[f], 16); sq[f] += __shfl_xor(sq[f], 16);
      st[f] += __shfl_xor(st[f], 32); sq[f] += __shfl_xor(sq[f], 32);
    }
    if (lg == 0) {
#pragma unroll
      for (int f = 0; f < 2; ++f) {
        int trip = wn * 32 + f * 16 + l15;
        P1S[trip * 2 + wm] = st[f];
        P1Q[trip * 2 + wm] = sq[f];
      }
    }
#pragma unroll
    for (int mf = 0; mf < 4; ++mf)
#pragma unroll
      for (int f = 0; f < 2; ++f) {
        int trip = wn * 32 + f * 16 + l15;
        uint2 w;
        w.x = pkbf(acc[mf][f][0], acc[mf][f][1]);
        w.y = pkbf(acc[mf][f][2], acc[mf][f][3]);
        *(uint2*)(smem + LDS_HM + trip * 256 +
                  ((wm * 128 + mf * 32 + lg * 8) ^ ((trip & 7) << 4))) = w;
      }
  }
  __syncthreads();

  // ---- GEMM2: C2' = W2'^T x H^T  (K=128), weights pipelined 1-deep ----
#pragma unroll
  for (int mf = 0; mf < 4; ++mf) { acc[mf][0] = (f32x4)0.f; acc[mf][1] = (f32x4)0.f; }
#pragma unroll
  for (int s4 = 0; s4 < 4; ++s4) {
    short8 w2n[4];
    if (s4 < 3) {
#pragma unroll
      for (int mf = 0; mf < 4; ++mf)
        w2n[mf] = w2p[(wm * 64 + mf * 16 + l15) * 16 + (s4 + 1) * 4 + lg];
    }
    short8 bx0, bx1;
    {
      int trip = wn * 32 + l15;
      bx0 = *(const short8*)(smem + LDS_HM + trip * 256 +
                             ((s4 * 64 + lg * 16) ^ ((trip & 7) << 4)));
      int trip2 = trip + 16;
      bx1 = *(const short8*)(smem + LDS_HM + trip2 * 256 +
                             ((s4 * 64 + lg * 16) ^ ((trip2 & 7) << 4)));
    }
    __builtin_amdgcn_s_setprio(1);
#pragma unroll
    for (int mf = 0; mf < 4; ++mf) {
      acc[mf][0] = MFMA16(w2c[mf], bx0, acc[mf][0]);
      acc[mf][1] = MFMA16(w2c[mf], bx1, acc[mf][1]);
    }
    __builtin_amdgcn_s_setprio(0);
    if (s4 < 3) {
#pragma unroll
      for (int mf = 0; mf < 4; ++mf) w2c[mf] = w2n[mf];
    }
  }

  // pre-issue GEMM3 step-0 weight frags (covered by epilogue-2 VALU)
  const short8* wb3 = (const short8*)wp3;
  short8 w3c[4];
#pragma unroll
  for (int nf = 0; nf < 4; ++nf)
    w3c[nf] = wb3[lg * 64 + nf * 16 + l15];

  // epilogue2: folded LN1 + silu; stats into P2
  {
    float4 s2f[4], c2f[4];
#pragma unroll
    for (int mf = 0; mf < 4; ++mf) {
      s2f[mf] = *(const float4*)(s2v + wm * 64 + mf * 16 + lg * 4);
      c2f[mf] = *(const float4*)(c2v + wm * 64 + mf * 16 + lg * 4);
    }
    float mu[2], inv[2];
#pragma unroll
    for (int f = 0; f < 2; ++f) {
      int trip = wn * 32 + f * 16 + l15;
      float sm = P1S[trip * 2] + P1S[trip * 2 + 1];
      float qq = P1Q[trip * 2] + P1Q[trip * 2 + 1];
      mu[f] = sm * 0.0078125f;
      inv[f] = rsqrtf(fmaxf(qq * 0.0078125f - mu[f] * mu[f], 0.f) + 1e-5f);
    }
    float st[2] = {0.f, 0.f}, sq[2] = {0.f, 0.f};
#pragma unroll
    for (int mf = 0; mf < 4; ++mf)
#pragma unroll
      for (int f = 0; f < 2; ++f)
#pragma unroll
        for (int q = 0; q < 4; ++q) {
          float y = inv[f] * (acc[mf][f][q] - mu[f] * s2f[mf][q]) + c2f[mf][q];
          float v = silu(y);
          acc[mf][f][q] = v;
          st[f] += v; sq[f] += v * v;
        }
#pragma unroll
    for (int f = 0; f < 2; ++f) {
      st[f] += __shfl_xor(st[f], 16); sq[f] += __shfl_xor(sq[f], 16);
      st[f] += __shfl_xor(st[f], 32); sq[f] += __shfl_xor(sq[f], 32);
    }
    if (lg == 0) {
#pragma unroll
      for (int f = 0; f < 2; ++f) {
        int trip = wn * 32 + f * 16 + l15;
        P2S[trip * 2 + wm] = st[f];
        P2Q[trip * 2 + wm] = sq[f];
      }
    }
  }
  __syncthreads();  // all GEMM2 H-reads done; P2 visible

  // write M [trip][n] bf16 into HM region (aliases H)
#pragma unroll
  for (int mf = 0; mf < 4; ++mf)
#pragma unroll
    for (int f = 0; f < 2; ++f) {
      int trip = wn * 32 + f * 16 + l15;
      uint2 w;
      w.x = pkbf(acc[mf][f][0], acc[mf][f][1]);
      w.y = pkbf(acc[mf][f][2], acc[mf][f][3]);
      *(uint2*)(smem + LDS_HM + trip * 256 +
                ((wm * 128 + mf * 32 + lg * 8) ^ ((trip & 7) << 4))) = w;
    }
  __syncthreads();  // M visible

  // ---- GEMM3 (un-transposed): C3 = M x W3'  (K=128, N=64), weights pipelined ----
  f32x4 acc3[4];
#pragma unroll
  for (int nf = 0; nf < 4; ++nf) acc3[nf] = (f32x4)0.f;
#pragma unroll
  for (int s4 = 0; s4 < 4; ++s4) {
    short8 w3n[4];
    if (s4 < 3) {
#pragma unroll
      for (int nf = 0; nf < 4; ++nf)
        w3n[nf] = wb3[((s4 + 1) * 4 + lg) * 64 + nf * 16 + l15];
    }
    int row = wave * 16 + l15;
    short8 a = *(const short8*)(smem + LDS_HM + row * 256 +
                                ((s4 * 64 + lg * 16) ^ ((row & 7) << 4)));
    __builtin_amdgcn_s_setprio(1);
#pragma unroll
    for (int nf = 0; nf < 4; ++nf) acc3[nf] = MFMA16(a, w3c[nf], acc3[nf]);
    __builtin_amdgcn_s_setprio(0);
    if (s4 < 3) {
#pragma unroll
      for (int nf = 0; nf < 4; ++nf) w3c[nf] = w3n[nf];
    }
  }
  {
    float s3c[4];
#pragma unroll
    for (int nf = 0; nf < 4; ++nf) s3c[nf] = s3v[nf * 16 + l15];
#pragma unroll
    for (int q = 0; q < 4; ++q) {
      int row = wave * 16 + lg * 4 + q;
      float sm = P2S[row * 2] + P2S[row * 2 + 1];
      float qq = P2Q[row * 2] + P2Q[row * 2 + 1];
      float mu = sm * 0.0078125f;
      float inv = rsqrtf(fmaxf(qq * 0.0078125f - mu * mu, 0.f) + 1e-5f);
      float* base = psum + (size_t)EIJ[row] * 64;
#pragma unroll
      for (int nf = 0; nf < 4; ++nf) {
        float y = inv * (acc3[nf][q] - mu * s3c[nf]);
        atomicAdd(base + nf * 16 + l15, y);
      }
    }
  }
}

// ---------------- finalize ----------------
// out = LN(ef + psum/max(cnt,1) + b3 + (cnt>0 ? t3 : 0), gn, bn)

__global__ __launch_bounds__(256) void k_final(
    const float* __restrict__ psum, const float* __restrict__ cnt,
    const float* __restrict__ ef, const float* __restrict__ b3,
    const float* __restrict__ t3, const float* __restrict__ gn,
    const float* __restrict__ bn, float* __restrict__ out) {
  int g = blockIdx.x * 256 + threadIdx.x;  // 4e6 threads, 4 lanes/edge
  int e = g >> 2, s = g & 3;
  float cv = cnt[e];
  float ic = 1.0f / fmaxf(cv, 1.0f);
  float tw = (cv > 0.f) ? 1.0f : 0.0f;
  float x[16];
  const float4* ps = (const float4*)(psum + (size_t)e * 64 + s * 16);
  const float4* fe = (const float4*)(ef + (size_t)e * 64 + s * 16);
  const float4* p3 = (const float4*)(b3 + s * 16);
  const float4* pt = (const float4*)(t3 + s * 16);
#pragma unroll
  for (int i = 0; i < 4; ++i) {
    float4 a = ps[i], b = fe[i], c = p3[i], d = pt[i];
    x[4 * i + 0] = b.x + a.x * ic + c.x + tw * d.x;
    x[4 * i + 1] = b.y + a.y * ic + c.y + tw * d.y;
    x[4 * i + 2] = b.z + a.z * ic + c.z + tw * d.z;
    x[4 * i + 3] = b.w + a.w * ic + c.w + tw * d.w;
  }
  float sum = 0.f, ss = 0.f;
#pragma unroll
  for (int i = 0; i < 16; ++i) { sum += x[i]; ss += x[i] * x[i]; }
  sum += __shfl_xor(sum, 1); ss += __shfl_xor(ss, 1);
  sum += __shfl_xor(sum, 2); ss += __shfl_xor(ss, 2);
  float mu = sum * (1.0f / 64.0f);
  float inv = rsqrtf(ss * (1.0f / 64.0f) - mu * mu + 1e-5f);
  float4* po = (float4*)(out + (size_t)e * 64 + s * 16);
#pragma unroll
  for (int i = 0; i < 4; ++i) {
    float4 gv = ((const float4*)(gn + s * 16))[i];
    float4 bv = ((const float4*)(bn + s * 16))[i];
    float4 o;
    o.x = (x[4 * i + 0] - mu) * inv * gv.x + bv.x;
    o.y = (x[4 * i + 1] - mu) * inv * gv.y + bv.y;
    o.z = (x[4 * i + 2] - mu) * inv * gv.z + bv.z;
    o.w = (x[4 * i + 3] - mu) * inv * gv.w + bv.w;
    po[i] = o;
  }
}

extern "C" void kernel_launch(void* const* d_in, const int* in_sizes, int n_in,
                              void* d_out, int out_size, void* d_ws, size_t ws_size,
                              hipStream_t stream) {
  const float* edge_feat = (const float*)d_in[0];
  const int* tidx = (const int*)d_in[1];
  const float* geo = (const float*)d_in[2];
  const float* W1 = (const float*)d_in[3];
  const float* b1 = (const float*)d_in[4];
  const float* g1 = (const float*)d_in[5];
  const float* be1 = (const float*)d_in[6];
  const float* W2 = (const float*)d_in[7];
  const float* b2 = (const float*)d_in[8];
  const float* g2 = (const float*)d_in[9];
  const float* be2 = (const float*)d_in[10];
  const float* W3 = (const float*)d_in[11];
  const float* b3 = (const float*)d_in[12];
  const float* gn = (const float*)d_in[13];
  const float* bn = (const float*)d_in[14];

  char* ws = (char*)d_ws;
  float* psum = (float*)(ws + OFF_PSUM);
  float* cnt = (float*)(ws + OFF_CNT);
  u16* ebf = (u16*)(ws + OFF_EBF);
  u16* wt1 = (u16*)(ws + OFF_WT1);
  u16* wt2 = (u16*)(ws + OFF_WT2);
  u16* wp3 = (u16*)(ws + OFF_WP3);
  float* s2 = (float*)(ws + OFF_S2);
  float* c2 = (float*)(ws + OFF_C2);
  float* s3 = (float*)(ws + OFF_S3);
  float* t3 = (float*)(ws + OFF_T3);
  float* out = (float*)d_out;

  hipMemsetAsync(ws, 0, 260000000ULL, stream);  // psum + cnt
  k_conv_edge<<<62500, 256, 0, stream>>>(edge_feat, ebf);
  k_pack_w<<<176, 256, 0, stream>>>(W1, W2, W3, g1, g2, wt1, wt2, wp3);
  k_pack_vec<<<1, 256, 0, stream>>>(W2, W3, g1, be1, b2, g2, be2, s2, c2, s3, t3);

  k_triplet<<<31250, 256, 0, stream>>>(ebf, tidx, geo, wt1, wt2, wp3,
                                       b1, s2, c2, s3, psum, cnt);
  k_final<<<15625, 256, 0, stream>>>(psum, cnt, edge_feat, b3, t3, gn, bn, out);
}